// Round 20
// baseline (137.857 us; speedup 1.0000x reference)
//
#include <hip/hip_runtime.h>
#include <hip/hip_bf16.h>

#define T_TOK 2048
#define H_DIM 1024
#define E_NUM 16
#define I_DIM 512
#define K_TOP 4
#define SI_DIM 1024

typedef __bf16 bf16x8 __attribute__((ext_vector_type(8)));
typedef __bf16 bf16x4 __attribute__((ext_vector_type(4)));
typedef float f32x4 __attribute__((ext_vector_type(4)));

#define GL2L(g, l)                                                                       \
  __builtin_amdgcn_global_load_lds((const __attribute__((address_space(1))) void*)(g),   \
                                   (__attribute__((address_space(3))) void*)(l), 16, 0, 0)
#define BAR() __builtin_amdgcn_s_barrier()

// -------- ALL weight transposes, 128x128 tiles (512B read / 256B write chunks) --------
// fp32 [Z,R,C] -> bf16 [Z,C,R]. Phase 1: 8 x (2 float4 -> bf16x8 ds_write, XOR-swizzled
// chunk = cb ^ (row&15)). Phase 2: thread owns col pair p (p=tid&63) and k-quarter
// (kq=tid>>6): per 8-k group, 8 wave-uniform-k ds_read_b32 (2 lanes/bank = free),
// v_perm de-interleave, 2x uint4 stores; 4 consecutive uint4 per row per thread.
__global__ __launch_bounds__(256) void transpose_all_kernel(
    const float* __restrict__ gate_w, const float* __restrict__ up_w,
    const float* __restrict__ down_w, const float* __restrict__ sgw,
    const float* __restrict__ suw, const float* __restrict__ sdw,
    const float* __restrict__ gate_weight, __bf16* __restrict__ gw_t,
    __bf16* __restrict__ uw_t, __bf16* __restrict__ dw_t, __bf16* __restrict__ sgw_t,
    __bf16* __restrict__ suw_t, __bf16* __restrict__ sdw_t, float* __restrict__ gwt_f) {
  int tid = threadIdx.x;
  int b = blockIdx.x;
  if (b >= 1728) {
    int bb = b - 1728;  // 16 blocks: gate_weight [H,16] -> [16,H]
#pragma unroll
    for (int k = 0; k < 4; k++) {
      int idx = k * 4096 + bb * 256 + tid;
      gwt_f[idx] = gate_weight[(idx & 1023) * E_NUM + (idx >> 10)];
    }
    return;
  }
  __shared__ __align__(16) __bf16 tile[128 * 128];  // 32KB
  const float* in;
  __bf16* out;
  int R, C, r0, c0;
  if (b < 1024) {
    bool g = b < 512;
    int bb = b & 511;
    int z = bb >> 5, ti = bb & 31;  // 8 r-tiles x 4 c-tiles
    R = H_DIM;
    C = I_DIM;
    r0 = (ti >> 2) * 128;
    c0 = (ti & 3) * 128;
    size_t off = (size_t)z * R * C;
    in = (g ? gate_w : up_w) + off;
    out = (g ? gw_t : uw_t) + off;
  } else if (b < 1536) {
    int bb = b - 1024;
    int z = bb >> 5, ti = bb & 31;  // 4 r-tiles x 8 c-tiles
    R = I_DIM;
    C = H_DIM;
    r0 = (ti >> 3) * 128;
    c0 = (ti & 7) * 128;
    size_t off = (size_t)z * R * C;
    in = down_w + off;
    out = dw_t + off;
  } else {
    int bb = b - 1536;
    int m = bb >> 6, ti = bb & 63;  // 8 x 8 tiles, 1024x1024
    R = 1024;
    C = 1024;
    r0 = (ti >> 3) * 128;
    c0 = (ti & 7) * 128;
    in = m == 0 ? sgw : m == 1 ? suw : sdw;
    out = m == 0 ? sgw_t : m == 1 ? suw_t : sdw_t;
  }
  // phase 1: global f32 -> bf16 -> LDS (rows read as 512B contiguous chunks)
#pragma unroll
  for (int q = 0; q < 8; q++) {
    int lin8 = q * 256 + tid;            // 2048 groups of 8 floats
    int row = lin8 >> 4, cb = lin8 & 15;
    const float* ip = in + (size_t)(r0 + row) * C + c0 + cb * 8;
    float4 v0 = *(const float4*)ip;
    float4 v1 = *(const float4*)(ip + 4);
    bf16x8 o;
    o[0] = (__bf16)v0.x; o[1] = (__bf16)v0.y; o[2] = (__bf16)v0.z; o[3] = (__bf16)v0.w;
    o[4] = (__bf16)v1.x; o[5] = (__bf16)v1.y; o[6] = (__bf16)v1.z; o[7] = (__bf16)v1.w;
    int pcb = cb ^ (row & 15);
    *(bf16x8*)&tile[row * 128 + pcb * 8] = o;
  }
  __syncthreads();
  // phase 2: column-pair gather + v_perm; 64B contiguous per row per 8-k group
  int p = tid & 63, kq = tid >> 6;
  int c = p * 2;
  const unsigned int* ldsw = (const unsigned int*)tile;
  __bf16* op0 = out + (size_t)(c0 + c) * R + r0 + kq * 32;
  __bf16* op1 = op0 + R;
#pragma unroll
  for (int j = 0; j < 4; j++) {
    unsigned int d[8];
#pragma unroll
    for (int i = 0; i < 8; i++) {
      int k = kq * 32 + j * 8 + i;
      int phys = (((p >> 2) ^ (k & 15)) << 2) + (p & 3);
      d[i] = ldsw[k * 64 + phys];
    }
    unsigned int lo[4], hi[4];
#pragma unroll
    for (int i = 0; i < 4; i++) {
      lo[i] = __builtin_amdgcn_perm(d[2 * i + 1], d[2 * i], 0x05040100u);
      hi[i] = __builtin_amdgcn_perm(d[2 * i + 1], d[2 * i], 0x07060302u);
    }
    *(uint4*)(op0 + j * 8) = make_uint4(lo[0], lo[1], lo[2], lo[3]);
    *(uint4*)(op1 + j * 8) = make_uint4(hi[0], hi[1], hi[2], hi[3]);
  }
}

// ---- router v3: gwt + x tiles in LDS (R18-proven). ----
__global__ __launch_bounds__(256) void router_kernel(
    const float* __restrict__ x, const float* __restrict__ gwt, const float* __restrict__ cbias,
    float* __restrict__ logits_out, __bf16* __restrict__ x_bf, int* __restrict__ selE,
    float* __restrict__ selW) {
  __shared__ float gw_lds[E_NUM * H_DIM];  // 64KB [e][h]
  __shared__ float x_lds[8 * H_DIM];       // 32KB
  int tid = threadIdx.x;
  int t0 = blockIdx.x * 8;
#pragma unroll
  for (int q = 0; q < 16; q++) {
    int i4 = q * 256 + tid;
    *(float4*)&gw_lds[i4 * 4] = *(const float4*)&gwt[i4 * 4];
  }
#pragma unroll
  for (int q = 0; q < 8; q++) {
    int i4 = q * 256 + tid;
    float4 v = *(const float4*)&x[(size_t)t0 * H_DIM + i4 * 4];
    *(float4*)&x_lds[i4 * 4] = v;
    bf16x4 o = {(__bf16)v.x, (__bf16)v.y, (__bf16)v.z, (__bf16)v.w};
    *(bf16x4*)&x_bf[(size_t)t0 * H_DIM + i4 * 4] = o;
  }
  __syncthreads();
  int wv = tid >> 6, lane = tid & 63;
  int tl = lane >> 5, hl = lane & 31;
  int t = t0 + wv * 2 + tl;
  float acc[E_NUM] = {};
  const float* xr = &x_lds[(wv * 2 + tl) * H_DIM];
#pragma unroll 4
  for (int hb = 0; hb < 32; hb++) {
    int h = hb * 32 + hl;
    float xv = xr[h];
#pragma unroll
    for (int e = 0; e < E_NUM; e++) acc[e] = fmaf(xv, gw_lds[e * H_DIM + h], acc[e]);
  }
#pragma unroll
  for (int mk = 1; mk <= 16; mk <<= 1)
#pragma unroll
    for (int e = 0; e < E_NUM; e++) acc[e] += __shfl_xor(acc[e], mk);
  if (hl == 0) {
#pragma unroll
    for (int e = 0; e < E_NUM; e++) logits_out[(size_t)t * E_NUM + e] = acc[e];
    float m = acc[0];
#pragma unroll
    for (int e = 1; e < E_NUM; e++) m = fmaxf(m, acc[e]);
    float p[E_NUM], s = 0.f;
#pragma unroll
    for (int e = 0; e < E_NUM; e++) {
      p[e] = __expf(acc[e] - m);
      s += p[e];
    }
    float inv = 1.f / s;
    float score[E_NUM];
#pragma unroll
    for (int e = 0; e < E_NUM; e++) {
      p[e] *= inv;
      score[e] = p[e] + cbias[e];
    }
    int sel[K_TOP];
    float w[K_TOP];
#pragma unroll
    for (int k = 0; k < K_TOP; k++) {
      int best = 0;
      float bv = -1e30f;
#pragma unroll
      for (int e = 0; e < E_NUM; e++)
        if (score[e] > bv) {
          bv = score[e];
          best = e;
        }
      score[best] = -1e30f;
      sel[k] = best;
      w[k] = p[best];
    }
    float wsum = fmaxf(w[0] + w[1] + w[2] + w[3], 1e-12f);
#pragma unroll
    for (int k = 0; k < K_TOP; k++) {
      selE[t * K_TOP + k] = sel[k];
      selW[t * K_TOP + k] = w[k] / wsum;
    }
  }
}

// ---------------- count + place, ONE block, ballot-based, zero global atomics ----------
__global__ __launch_bounds__(1024) void count_place_kernel(
    const int* __restrict__ selE, int* __restrict__ counts, int* __restrict__ offs,
    int* __restrict__ slot_of_tk, int* __restrict__ tok_of_slot) {
  int tid = threadIdx.x;
  int wv = tid >> 6, lane = tid & 63;
  unsigned long long lt = (1ULL << lane) - 1ULL;
  __shared__ int wcnt[16][16];
  __shared__ int wbase[16][16];
  __shared__ int glob[16];
  __shared__ int offsh[16];
  if (tid < 16) glob[tid] = 0;
  __syncthreads();
  int ex[8], rk[8];
#pragma unroll
  for (int r = 0; r < 8; r++) {
    int e = selE[r * 1024 + tid];
    ex[r] = e;
    int rank = 0;
#pragma unroll
    for (int q = 0; q < 16; q++) {
      unsigned long long b = __ballot(e == q);
      int c = __popcll(b & lt);
      if (e == q) rank = c;
      if (lane == q) wcnt[wv][q] = __popcll(b);
    }
    __syncthreads();
    if (wv == 0 && lane < 16) {
      int run = glob[lane];
#pragma unroll
      for (int w = 0; w < 16; w++) {
        wbase[w][lane] = run;
        run += wcnt[w][lane];
      }
      glob[lane] = run;
    }
    __syncthreads();
    rk[r] = rank + wbase[wv][e];
    __syncthreads();
  }
  if (wv == 0 && lane == 0) {
    int s = 0;
#pragma unroll
    for (int q = 0; q < 16; q++) {
      offsh[q] = s;
      s += glob[q];
    }
  }
  __syncthreads();
  if (tid < 16) {
    counts[tid] = glob[tid];
    offs[tid] = offsh[tid];
  }
#pragma unroll
  for (int r = 0; r < 8; r++) {
    int entry = r * 1024 + tid;
    int slot = offsh[ex[r]] + rk[r];
    slot_of_tk[entry] = slot;
    tok_of_slot[slot] = entry >> 2;
  }
}

// stage 1 FUSED, 128x64 tile — K9 schedule VERBATIM (best measured).
__global__ __launch_bounds__(256, 3) void gemm_stage1(
    const __bf16* __restrict__ x_bf, const int* __restrict__ tok_of_slot,
    const int* __restrict__ counts, const int* __restrict__ offs, const __bf16* __restrict__ gw_t,
    const __bf16* __restrict__ uw_t, const __bf16* __restrict__ sgw_t,
    const __bf16* __restrict__ suw_t, __bf16* __restrict__ he, __bf16* __restrict__ hs) {
  __shared__ __align__(16) __bf16 Alds[128 * 64];    // 16KB
  __shared__ __align__(16) __bf16 Bgl[2 * 64 * 64];  // 16KB (dbuf)
  __shared__ __align__(16) __bf16 Bul[2 * 64 * 64];  // 16KB (dbuf)
  int z = blockIdx.z, bx = blockIdx.x, m0 = blockIdx.y * 128;
  const __bf16 *Bg, *Bu;
  __bf16* Cp;
  const int* tokIdx;
  int rowOff, M, ldC, n0;
  if (z < E_NUM) {
    M = counts[z];
    if (m0 >= M) return;
    tokIdx = tok_of_slot;
    rowOff = offs[z];
    Bg = gw_t + (size_t)z * I_DIM * H_DIM;
    Bu = uw_t + (size_t)z * I_DIM * H_DIM;
    Cp = he;
    ldC = I_DIM;
    n0 = bx * 64;
  } else {
    tokIdx = nullptr;
    rowOff = 0;
    M = T_TOK;
    Bg = sgw_t;
    Bu = suw_t;
    Cp = hs;
    ldC = SI_DIM;
    n0 = (z - E_NUM) * 512 + bx * 64;  // z = 16,17 cover SI_DIM = 1024
  }
  int tid = threadIdx.x;
  int wave = tid >> 6, lane = tid & 63;
  int rsub = lane >> 3, chunk = lane & 7;
  int sch = (chunk ^ rsub) * 8;
  size_t aB[4], bB[2];
#pragma unroll
  for (int j = 0; j < 4; j++) {
    int r = wave * 32 + j * 8 + rsub;
    int ar = m0 + r;
    ar = ar < M - 1 ? ar : M - 1;
    int grow = tokIdx ? tokIdx[rowOff + ar] : rowOff + ar;
    aB[j] = (size_t)grow * H_DIM + sch;
  }
#pragma unroll
  for (int j = 0; j < 2; j++) {
    int r = wave * 16 + j * 8 + rsub;
    bB[j] = (size_t)(n0 + r) * H_DIM + sch;
  }
  int wm = (wave >> 1) * 64, wn = (wave & 1) * 32;
  int rl = lane & 15, gq = lane >> 4;
  int xa = rl & 7;

  auto STAGE_A = [&](int k0) {
#pragma unroll
    for (int j = 0; j < 4; j++) GL2L(x_bf + aB[j] + k0, Alds + (wave * 32 + j * 8) * 64);
  };
  auto STAGE_B = [&](int k0, int buf) {
#pragma unroll
    for (int j = 0; j < 2; j++) {
      int ld = buf * 4096 + (wave * 16 + j * 8) * 64;
      GL2L(Bg + bB[j] + k0, Bgl + ld);
      GL2L(Bu + bB[j] + k0, Bul + ld);
    }
  };

  f32x4 accg[4][2] = {}, accu[4][2] = {};
  const int NT = H_DIM / 64;  // 16
  STAGE_A(0);
  STAGE_B(0, 0);
  int buf = 0;
  for (int t = 0; t < NT; ++t) {
    if (t + 1 < NT) {
      STAGE_B((t + 1) << 6, buf ^ 1);
      asm volatile("s_waitcnt vmcnt(4)" ::: "memory");
    } else {
      asm volatile("s_waitcnt vmcnt(0)" ::: "memory");
    }
    BAR();
    const __bf16* Bgr = Bgl + buf * 4096;
    const __bf16* Bur = Bul + buf * 4096;
#pragma unroll
    for (int s = 0; s < 2; s++) {
      int lc = ((s * 4 + gq) ^ xa) * 8;
      bf16x8 af[4], bg[2], bu[2];
#pragma unroll
      for (int m = 0; m < 4; m++) af[m] = *(const bf16x8*)&Alds[(wm + m * 16 + rl) * 64 + lc];
#pragma unroll
      for (int n = 0; n < 2; n++) {
        bg[n] = *(const bf16x8*)&Bgr[(wn + n * 16 + rl) * 64 + lc];
        bu[n] = *(const bf16x8*)&Bur[(wn + n * 16 + rl) * 64 + lc];
      }
#pragma unroll
      for (int m = 0; m < 4; m++)
#pragma unroll
        for (int n = 0; n < 2; n++) {
          accg[m][n] =
              __builtin_amdgcn_mfma_f32_16x16x32_bf16(af[m], bg[n], accg[m][n], 0, 0, 0);
          accu[m][n] =
              __builtin_amdgcn_mfma_f32_16x16x32_bf16(af[m], bu[n], accu[m][n], 0, 0, 0);
        }
    }
    BAR();
    if (t + 1 < NT) STAGE_A((t + 1) << 6);
    buf ^= 1;
  }
#pragma unroll
  for (int m = 0; m < 4; m++) {
#pragma unroll
    for (int b = 0; b < 4; b++) {
      int row = m0 + wm + m * 16 + gq * 4 + b;
      if (row < M) {
        size_t rb = (size_t)(rowOff + row) * ldC + n0 + wn + rl;
#pragma unroll
        for (int n = 0; n < 2; n++) {
          float g = accg[m][n][b];
          float u = accu[m][n][b];
          float h = g / (1.f + __expf(-g)) * u;
          Cp[rb + n * 16] = (__bf16)h;
        }
      }
    }
  }
}

// stage 2, 64x64 tile — K9 schedule (B 2 loads/iter -> vmcnt(2)).
__global__ __launch_bounds__(256, 4) void gemm_stage2(
    const __bf16* __restrict__ he, const __bf16* __restrict__ hs, const int* __restrict__ counts,
    const int* __restrict__ offs, const __bf16* __restrict__ dw_t,
    const __bf16* __restrict__ sdw_t, __bf16* __restrict__ eo, __bf16* __restrict__ so) {
  __shared__ __align__(16) __bf16 Alds[64 * 64];      // 8KB
  __shared__ __align__(16) __bf16 Blds[2 * 64 * 64];  // 16KB (dbuf)
  int z = blockIdx.z, bx = blockIdx.x, m0 = blockIdx.y * 64;
  const __bf16 *A, *Bp;
  __bf16* Cp;
  int rowOff, M, K;
  if (z < E_NUM) {
    M = counts[z];
    if (m0 >= M) return;
    A = he;
    rowOff = offs[z];
    K = I_DIM;
    Bp = dw_t + (size_t)z * H_DIM * I_DIM;
    Cp = eo;
  } else {
    A = hs;
    rowOff = 0;
    M = T_TOK;
    K = SI_DIM;
    Bp = sdw_t;
    Cp = so;
  }
  int n0 = bx * 64;
  int tid = threadIdx.x;
  int wave = tid >> 6, lane = tid & 63;
  int rsub = lane >> 3, chunk = lane & 7;
  int sch = (chunk ^ rsub) * 8;
  size_t aB[2], bB[2];
#pragma unroll
  for (int j = 0; j < 2; j++) {
    int r = wave * 16 + j * 8 + rsub;
    int ar = m0 + r;
    ar = ar < M - 1 ? ar : M - 1;
    aB[j] = (size_t)(rowOff + ar) * K + sch;
    bB[j] = (size_t)(n0 + r) * K + sch;
  }
  int wm = (wave >> 1) * 32, wn = (wave & 1) * 32;
  int rl = lane & 15, gq = lane >> 4;
  int xa = rl & 7;

  auto STAGE_A = [&](int k0) {
#pragma unroll
    for (int j = 0; j < 2; j++) GL2L(A + aB[j] + k0, Alds + (wave * 16 + j * 8) * 64);
  };
  auto STAGE_B = [&](int k0, int b) {
#pragma unroll
    for (int j = 0; j < 2; j++)
      GL2L(Bp + bB[j] + k0, Blds + b * 4096 + (wave * 16 + j * 8) * 64);
  };

  f32x4 acc[2][2] = {};
  const int NT = K >> 6;
  STAGE_A(0);
  STAGE_B(0, 0);
  int buf = 0;
  for (int t = 0; t < NT; ++t) {
    if (t + 1 < NT) {
      STAGE_B((t + 1) << 6, buf ^ 1);
      asm volatile("s_waitcnt vmcnt(2)" ::: "memory");
    } else {
      asm volatile("s_waitcnt vmcnt(0)" ::: "memory");
    }
    BAR();
    const __bf16* Br = Blds + buf * 4096;
#pragma unroll
    for (int s = 0; s < 2; s++) {
      int lc = ((s * 4 + gq) ^ xa) * 8;
      bf16x8 af[2], bfr[2];
#pragma unroll
      for (int m = 0; m < 2; m++) af[m] = *(const bf16x8*)&Alds[(wm + m * 16 + rl) * 64 + lc];
#pragma unroll
      for (int n = 0; n < 2; n++) bfr[n] = *(const bf16x8*)&Br[(wn + n * 16 + rl) * 64 + lc];
#pragma unroll
      for (int m = 0; m < 2; m++)
#pragma unroll
        for (int n = 0; n < 2; n++)
          acc[m][n] =
              __builtin_amdgcn_mfma_f32_16x16x32_bf16(af[m], bfr[n], acc[m][n], 0, 0, 0);
    }
    BAR();
    if (t + 1 < NT) STAGE_A((t + 1) << 6);
    buf ^= 1;
  }
#pragma unroll
  for (int m = 0; m < 2; m++) {
#pragma unroll
    for (int b = 0; b < 4; b++) {
      int row = m0 + wm + m * 16 + gq * 4 + b;
      if (row < M) {
        size_t rb = (size_t)(rowOff + row) * H_DIM + n0 + wn + rl;
#pragma unroll
        for (int n = 0; n < 2; n++) Cp[rb + n * 16] = (__bf16)acc[m][n][b];
      }
    }
  }
}

// ---------------- combine: out = shared + sum_k w_k * eo[slot_k] ----------------
__global__ void combine_kernel(const __bf16* __restrict__ eo, const __bf16* __restrict__ so,
                               const int* __restrict__ slot_of_tk, const float* __restrict__ selW,
                               float* __restrict__ out) {
  int idx = blockIdx.x * blockDim.x + threadIdx.x;
  int t = idx >> 8;
  int h4 = (idx & 255) * 4;
  if (t >= T_TOK) return;
  bf16x4 sv = *(const bf16x4*)(so + (size_t)t * H_DIM + h4);
  float a0 = (float)sv[0], a1 = (float)sv[1], a2 = (float)sv[2], a3 = (float)sv[3];
#pragma unroll
  for (int k = 0; k < K_TOP; k++) {
    int slot = slot_of_tk[t * K_TOP + k];
    float w = selW[t * K_TOP + k];
    bf16x4 ev = *(const bf16x4*)(eo + (size_t)slot * H_DIM + h4);
    a0 += w * (float)ev[0];
    a1 += w * (float)ev[1];
    a2 += w * (float)ev[2];
    a3 += w * (float)ev[3];
  }
  *(float4*)(out + (size_t)t * H_DIM + h4) = make_float4(a0, a1, a2, a3);
}

extern "C" void kernel_launch(void* const* d_in, const int* in_sizes, int n_in, void* d_out,
                              int out_size, void* d_ws, size_t ws_size, hipStream_t stream) {
  const float* x = (const float*)d_in[0];
  const float* gate_weight = (const float*)d_in[1];
  const float* corr_bias = (const float*)d_in[2];
  const float* gate_w = (const float*)d_in[3];
  const float* up_w = (const float*)d_in[4];
  const float* down_w = (const float*)d_in[5];
  const float* sgw = (const float*)d_in[6];
  const float* suw = (const float*)d_in[7];
  const float* sdw = (const float*)d_in[8];
  float* out = (float*)d_out;
  float* logits_out = out + (size_t)T_TOK * H_DIM;

  char* wsb = (char*)d_ws;
  size_t o = 0;
  auto nxt = [&](size_t bytes) -> void* {
    void* p = wsb + o;
    o += (bytes + 1023) & ~(size_t)1023;
    return p;
  };
  const size_t EXP_ELE = (size_t)T_TOK * K_TOP * I_DIM;  // 4M
  const size_t SH_ELE = (size_t)T_TOK * SI_DIM;          // 2M
  __bf16* x_bf = (__bf16*)nxt((size_t)T_TOK * H_DIM * 2);
  __bf16* gw_t = (__bf16*)nxt((size_t)E_NUM * I_DIM * H_DIM * 2);  // [E, I, H]
  __bf16* uw_t = (__bf16*)nxt((size_t)E_NUM * I_DIM * H_DIM * 2);
  __bf16* dw_t = (__bf16*)nxt((size_t)E_NUM * H_DIM * I_DIM * 2);  // [E, H, I]
  __bf16* sgw_t = (__bf16*)nxt((size_t)SI_DIM * H_DIM * 2);        // [SI, H]
  __bf16* suw_t = (__bf16*)nxt((size_t)SI_DIM * H_DIM * 2);
  __bf16* sdw_t = (__bf16*)nxt((size_t)H_DIM * SI_DIM * 2);  // [H, SI]
  __bf16* h_all = (__bf16*)nxt((EXP_ELE + SH_ELE) * 2);
  __bf16* eo = (__bf16*)nxt((size_t)T_TOK * K_TOP * H_DIM * 2);
  __bf16* so = (__bf16*)nxt((size_t)T_TOK * H_DIM * 2);
  float* gwt_f = (float*)nxt((size_t)E_NUM * H_DIM * 4);
  int* counts = (int*)nxt(64);
  int* offs = (int*)nxt(128);
  int* selE = (int*)nxt((size_t)T_TOK * K_TOP * 4);
  float* selW = (float*)nxt((size_t)T_TOK * K_TOP * 4);
  int* slot_of_tk = (int*)nxt((size_t)T_TOK * K_TOP * 4);
  int* tok_of_slot = (int*)nxt((size_t)T_TOK * K_TOP * 4);
  __bf16* he = h_all;
  __bf16* hs = h_all + EXP_ELE;
  (void)ws_size;
  (void)in_sizes;
  (void)n_in;
  (void)out_size;

  transpose_all_kernel<<<1744, 256, 0, stream>>>(gate_w, up_w, down_w, sgw, suw, sdw,
                                                 gate_weight, gw_t, uw_t, dw_t, sgw_t, suw_t,
                                                 sdw_t, gwt_f);
  router_kernel<<<T_TOK / 8, 256, 0, stream>>>(x, gwt_f, corr_bias, logits_out, x_bf, selE,
                                               selW);
  count_place_kernel<<<1, 1024, 0, stream>>>(selE, counts, offs, slot_of_tk, tok_of_slot);

  gemm_stage1<<<dim3(8, 16, E_NUM + 2), 256, 0, stream>>>(x_bf, tok_of_slot, counts, offs, gw_t,
                                                          uw_t, sgw_t, suw_t, he, hs);
  gemm_stage2<<<dim3(16, 32, E_NUM + 1), 256, 0, stream>>>(he, hs, counts, offs, dw_t, sdw_t, eo,
                                                           so);

  combine_kernel<<<(T_TOK * H_DIM / 4) / 256, 256, 0, stream>>>(eo, so, slot_of_tk, selW, out);
}

// Round 21
// 131.358 us; speedup vs baseline: 1.0495x; 1.0495x over previous
//
#include <hip/hip_runtime.h>
#include <hip/hip_bf16.h>

#define T_TOK 2048
#define H_DIM 1024
#define E_NUM 16
#define I_DIM 512
#define K_TOP 4
#define SI_DIM 1024

typedef __bf16 bf16x8 __attribute__((ext_vector_type(8)));
typedef __bf16 bf16x4 __attribute__((ext_vector_type(4)));
typedef float f32x4 __attribute__((ext_vector_type(4)));

#define GL2L(g, l)                                                                       \
  __builtin_amdgcn_global_load_lds((const __attribute__((address_space(1))) void*)(g),   \
                                   (__attribute__((address_space(3))) void*)(l), 16, 0, 0)
#define BAR() __builtin_amdgcn_s_barrier()

// -------- ALL weight transposes, LDS-op-minimized: fp32 [Z,R,C] -> bf16 [Z,C,R] -----
// (R18-proven best: 46-47us, 0 bank conflicts.)
__global__ __launch_bounds__(256) void transpose_all_kernel(
    const float* __restrict__ gate_w, const float* __restrict__ up_w,
    const float* __restrict__ down_w, const float* __restrict__ sgw,
    const float* __restrict__ suw, const float* __restrict__ sdw,
    const float* __restrict__ gate_weight, __bf16* __restrict__ gw_t,
    __bf16* __restrict__ uw_t, __bf16* __restrict__ dw_t, __bf16* __restrict__ sgw_t,
    __bf16* __restrict__ suw_t, __bf16* __restrict__ sdw_t, float* __restrict__ gwt_f) {
  int tid = threadIdx.x;
  if (blockIdx.x >= 6912) {
    int b = blockIdx.x - 6912;  // 16 blocks
#pragma unroll
    for (int k = 0; k < 4; k++) {
      int idx = k * 4096 + b * 256 + tid;  // e*1024 + h
      gwt_f[idx] = gate_weight[(idx & 1023) * E_NUM + (idx >> 10)];
    }
    return;
  }
  __shared__ __align__(16) __bf16 tile[64 * 64];  // 8KB, XOR-swizzled
  int t = blockIdx.x;
  const float* in;
  __bf16* out;
  int R, C, r0, c0;
  if (t < 4096) {
    bool g = t < 2048;
    int b = t & 2047;
    int z = b >> 7;
    int ti = b & 127;
    R = H_DIM;
    C = I_DIM;
    r0 = (ti >> 3) * 64;
    c0 = (ti & 7) * 64;
    size_t off = (size_t)z * R * C;
    in = (g ? gate_w : up_w) + off;
    out = (g ? gw_t : uw_t) + off;
  } else if (t < 6144) {
    int b = t - 4096;
    int z = b >> 7;
    int ti = b & 127;
    R = I_DIM;
    C = H_DIM;
    r0 = (ti >> 4) * 64;
    c0 = (ti & 15) * 64;
    size_t off = (size_t)z * R * C;
    in = down_w + off;
    out = dw_t + off;
  } else {
    int b = t - 6144;
    int m = b >> 8;
    int ti = b & 255;
    R = 1024;
    C = 1024;
    r0 = (ti >> 4) * 64;
    c0 = (ti & 15) * 64;
    in = m == 0 ? sgw : m == 1 ? suw : sdw;
    out = m == 0 ? sgw_t : m == 1 ? suw_t : sdw_t;
  }
  // phase 1: global f32 -> bf16 -> LDS (b128, swizzled)
#pragma unroll
  for (int q = 0; q < 2; q++) {
    int lin8 = q * 256 + tid;
    int row = lin8 >> 3, cb = lin8 & 7;
    const float* ip = in + (size_t)(r0 + row) * C + c0 + cb * 8;
    float4 v0 = *(const float4*)ip;
    float4 v1 = *(const float4*)(ip + 4);
    bf16x8 o;
    o[0] = (__bf16)v0.x; o[1] = (__bf16)v0.y; o[2] = (__bf16)v0.z; o[3] = (__bf16)v0.w;
    o[4] = (__bf16)v1.x; o[5] = (__bf16)v1.y; o[6] = (__bf16)v1.z; o[7] = (__bf16)v1.w;
    int pcb = cb ^ ((row >> 3) & 7);
    *(bf16x8*)&tile[row * 64 + pcb * 8] = o;
  }
  __syncthreads();
  // phase 2: column-pair gather via b32 reads + v_perm de-interleave
  int p = tid >> 3, seg = tid & 7;
  int c = p * 2;
  const unsigned int* ldsw = (const unsigned int*)tile;
  unsigned int d[8];
#pragma unroll
  for (int i = 0; i < 8; i++) {
    int r = seg * 8 + i;
    int pcb = (p >> 2) ^ seg;
    d[i] = ldsw[r * 32 + pcb * 4 + (p & 3)];
  }
  unsigned int lo[4], hi[4];
#pragma unroll
  for (int j = 0; j < 4; j++) {
    lo[j] = __builtin_amdgcn_perm(d[2 * j + 1], d[2 * j], 0x05040100u);
    hi[j] = __builtin_amdgcn_perm(d[2 * j + 1], d[2 * j], 0x07060302u);
  }
  __bf16* op0 = out + (size_t)(c0 + c) * R + r0 + seg * 8;
  __bf16* op1 = op0 + R;
  *(uint4*)op0 = make_uint4(lo[0], lo[1], lo[2], lo[3]);
  *(uint4*)op1 = make_uint4(hi[0], hi[1], hi[2], hi[3]);
}

// ---- router v3: gwt + x tiles in LDS (R18-proven). ----
__global__ __launch_bounds__(256) void router_kernel(
    const float* __restrict__ x, const float* __restrict__ gwt, const float* __restrict__ cbias,
    float* __restrict__ logits_out, __bf16* __restrict__ x_bf, int* __restrict__ selE,
    float* __restrict__ selW) {
  __shared__ float gw_lds[E_NUM * H_DIM];  // 64KB [e][h]
  __shared__ float x_lds[8 * H_DIM];       // 32KB
  int tid = threadIdx.x;
  int t0 = blockIdx.x * 8;
#pragma unroll
  for (int q = 0; q < 16; q++) {
    int i4 = q * 256 + tid;
    *(float4*)&gw_lds[i4 * 4] = *(const float4*)&gwt[i4 * 4];
  }
#pragma unroll
  for (int q = 0; q < 8; q++) {
    int i4 = q * 256 + tid;
    float4 v = *(const float4*)&x[(size_t)t0 * H_DIM + i4 * 4];
    *(float4*)&x_lds[i4 * 4] = v;
    bf16x4 o = {(__bf16)v.x, (__bf16)v.y, (__bf16)v.z, (__bf16)v.w};
    *(bf16x4*)&x_bf[(size_t)t0 * H_DIM + i4 * 4] = o;
  }
  __syncthreads();
  int wv = tid >> 6, lane = tid & 63;
  int tl = lane >> 5, hl = lane & 31;
  int t = t0 + wv * 2 + tl;
  float acc[E_NUM] = {};
  const float* xr = &x_lds[(wv * 2 + tl) * H_DIM];
#pragma unroll 4
  for (int hb = 0; hb < 32; hb++) {
    int h = hb * 32 + hl;
    float xv = xr[h];
#pragma unroll
    for (int e = 0; e < E_NUM; e++) acc[e] = fmaf(xv, gw_lds[e * H_DIM + h], acc[e]);
  }
#pragma unroll
  for (int mk = 1; mk <= 16; mk <<= 1)
#pragma unroll
    for (int e = 0; e < E_NUM; e++) acc[e] += __shfl_xor(acc[e], mk);
  if (hl == 0) {
#pragma unroll
    for (int e = 0; e < E_NUM; e++) logits_out[(size_t)t * E_NUM + e] = acc[e];
    float m = acc[0];
#pragma unroll
    for (int e = 1; e < E_NUM; e++) m = fmaxf(m, acc[e]);
    float p[E_NUM], s = 0.f;
#pragma unroll
    for (int e = 0; e < E_NUM; e++) {
      p[e] = __expf(acc[e] - m);
      s += p[e];
    }
    float inv = 1.f / s;
    float score[E_NUM];
#pragma unroll
    for (int e = 0; e < E_NUM; e++) {
      p[e] *= inv;
      score[e] = p[e] + cbias[e];
    }
    int sel[K_TOP];
    float w[K_TOP];
#pragma unroll
    for (int k = 0; k < K_TOP; k++) {
      int best = 0;
      float bv = -1e30f;
#pragma unroll
      for (int e = 0; e < E_NUM; e++)
        if (score[e] > bv) {
          bv = score[e];
          best = e;
        }
      score[best] = -1e30f;
      sel[k] = best;
      w[k] = p[best];
    }
    float wsum = fmaxf(w[0] + w[1] + w[2] + w[3], 1e-12f);
#pragma unroll
    for (int k = 0; k < K_TOP; k++) {
      selE[t * K_TOP + k] = sel[k];
      selW[t * K_TOP + k] = w[k] / wsum;
    }
  }
}

// ---------------- count + place, ONE block, ballot-based, zero global atomics ----------
__global__ __launch_bounds__(1024) void count_place_kernel(
    const int* __restrict__ selE, int* __restrict__ counts, int* __restrict__ offs,
    int* __restrict__ slot_of_tk, int* __restrict__ tok_of_slot) {
  int tid = threadIdx.x;
  int wv = tid >> 6, lane = tid & 63;
  unsigned long long lt = (1ULL << lane) - 1ULL;
  __shared__ int wcnt[16][16];
  __shared__ int wbase[16][16];
  __shared__ int glob[16];
  __shared__ int offsh[16];
  if (tid < 16) glob[tid] = 0;
  __syncthreads();
  int ex[8], rk[8];
#pragma unroll
  for (int r = 0; r < 8; r++) {
    int e = selE[r * 1024 + tid];
    ex[r] = e;
    int rank = 0;
#pragma unroll
    for (int q = 0; q < 16; q++) {
      unsigned long long b = __ballot(e == q);
      int c = __popcll(b & lt);
      if (e == q) rank = c;
      if (lane == q) wcnt[wv][q] = __popcll(b);
    }
    __syncthreads();
    if (wv == 0 && lane < 16) {
      int run = glob[lane];
#pragma unroll
      for (int w = 0; w < 16; w++) {
        wbase[w][lane] = run;
        run += wcnt[w][lane];
      }
      glob[lane] = run;
    }
    __syncthreads();
    rk[r] = rank + wbase[wv][e];
    __syncthreads();
  }
  if (wv == 0 && lane == 0) {
    int s = 0;
#pragma unroll
    for (int q = 0; q < 16; q++) {
      offsh[q] = s;
      s += glob[q];
    }
  }
  __syncthreads();
  if (tid < 16) {
    counts[tid] = glob[tid];
    offs[tid] = offsh[tid];
  }
#pragma unroll
  for (int r = 0; r < 8; r++) {
    int entry = r * 1024 + tid;
    int slot = offsh[ex[r]] + rk[r];
    slot_of_tk[entry] = slot;
    tok_of_slot[slot] = entry >> 2;
  }
}

// stage 1 FUSED, 128x64 tile — K9 schedule VERBATIM (best measured).
__global__ __launch_bounds__(256, 3) void gemm_stage1(
    const __bf16* __restrict__ x_bf, const int* __restrict__ tok_of_slot,
    const int* __restrict__ counts, const int* __restrict__ offs, const __bf16* __restrict__ gw_t,
    const __bf16* __restrict__ uw_t, const __bf16* __restrict__ sgw_t,
    const __bf16* __restrict__ suw_t, __bf16* __restrict__ he, __bf16* __restrict__ hs) {
  __shared__ __align__(16) __bf16 Alds[128 * 64];    // 16KB
  __shared__ __align__(16) __bf16 Bgl[2 * 64 * 64];  // 16KB (dbuf)
  __shared__ __align__(16) __bf16 Bul[2 * 64 * 64];  // 16KB (dbuf)
  int z = blockIdx.z, bx = blockIdx.x, m0 = blockIdx.y * 128;
  const __bf16 *Bg, *Bu;
  __bf16* Cp;
  const int* tokIdx;
  int rowOff, M, ldC, n0;
  if (z < E_NUM) {
    M = counts[z];
    if (m0 >= M) return;
    tokIdx = tok_of_slot;
    rowOff = offs[z];
    Bg = gw_t + (size_t)z * I_DIM * H_DIM;
    Bu = uw_t + (size_t)z * I_DIM * H_DIM;
    Cp = he;
    ldC = I_DIM;
    n0 = bx * 64;
  } else {
    tokIdx = nullptr;
    rowOff = 0;
    M = T_TOK;
    Bg = sgw_t;
    Bu = suw_t;
    Cp = hs;
    ldC = SI_DIM;
    n0 = (z - E_NUM) * 512 + bx * 64;  // z = 16,17 cover SI_DIM = 1024
  }
  int tid = threadIdx.x;
  int wave = tid >> 6, lane = tid & 63;
  int rsub = lane >> 3, chunk = lane & 7;
  int sch = (chunk ^ rsub) * 8;
  size_t aB[4], bB[2];
#pragma unroll
  for (int j = 0; j < 4; j++) {
    int r = wave * 32 + j * 8 + rsub;
    int ar = m0 + r;
    ar = ar < M - 1 ? ar : M - 1;
    int grow = tokIdx ? tokIdx[rowOff + ar] : rowOff + ar;
    aB[j] = (size_t)grow * H_DIM + sch;
  }
#pragma unroll
  for (int j = 0; j < 2; j++) {
    int r = wave * 16 + j * 8 + rsub;
    bB[j] = (size_t)(n0 + r) * H_DIM + sch;
  }
  int wm = (wave >> 1) * 64, wn = (wave & 1) * 32;
  int rl = lane & 15, gq = lane >> 4;
  int xa = rl & 7;

  auto STAGE_A = [&](int k0) {
#pragma unroll
    for (int j = 0; j < 4; j++) GL2L(x_bf + aB[j] + k0, Alds + (wave * 32 + j * 8) * 64);
  };
  auto STAGE_B = [&](int k0, int buf) {
#pragma unroll
    for (int j = 0; j < 2; j++) {
      int ld = buf * 4096 + (wave * 16 + j * 8) * 64;
      GL2L(Bg + bB[j] + k0, Bgl + ld);
      GL2L(Bu + bB[j] + k0, Bul + ld);
    }
  };

  f32x4 accg[4][2] = {}, accu[4][2] = {};
  const int NT = H_DIM / 64;  // 16
  STAGE_A(0);
  STAGE_B(0, 0);
  int buf = 0;
  for (int t = 0; t < NT; ++t) {
    if (t + 1 < NT) {
      STAGE_B((t + 1) << 6, buf ^ 1);
      asm volatile("s_waitcnt vmcnt(4)" ::: "memory");
    } else {
      asm volatile("s_waitcnt vmcnt(0)" ::: "memory");
    }
    BAR();
    const __bf16* Bgr = Bgl + buf * 4096;
    const __bf16* Bur = Bul + buf * 4096;
#pragma unroll
    for (int s = 0; s < 2; s++) {
      int lc = ((s * 4 + gq) ^ xa) * 8;
      bf16x8 af[4], bg[2], bu[2];
#pragma unroll
      for (int m = 0; m < 4; m++) af[m] = *(const bf16x8*)&Alds[(wm + m * 16 + rl) * 64 + lc];
#pragma unroll
      for (int n = 0; n < 2; n++) {
        bg[n] = *(const bf16x8*)&Bgr[(wn + n * 16 + rl) * 64 + lc];
        bu[n] = *(const bf16x8*)&Bur[(wn + n * 16 + rl) * 64 + lc];
      }
#pragma unroll
      for (int m = 0; m < 4; m++)
#pragma unroll
        for (int n = 0; n < 2; n++) {
          accg[m][n] =
              __builtin_amdgcn_mfma_f32_16x16x32_bf16(af[m], bg[n], accg[m][n], 0, 0, 0);
          accu[m][n] =
              __builtin_amdgcn_mfma_f32_16x16x32_bf16(af[m], bu[n], accu[m][n], 0, 0, 0);
        }
    }
    BAR();
    if (t + 1 < NT) STAGE_A((t + 1) << 6);
    buf ^= 1;
  }
#pragma unroll
  for (int m = 0; m < 4; m++) {
#pragma unroll
    for (int b = 0; b < 4; b++) {
      int row = m0 + wm + m * 16 + gq * 4 + b;
      if (row < M) {
        size_t rb = (size_t)(rowOff + row) * ldC + n0 + wn + rl;
#pragma unroll
        for (int n = 0; n < 2; n++) {
          float g = accg[m][n][b];
          float u = accu[m][n][b];
          float h = g / (1.f + __expf(-g)) * u;
          Cp[rb + n * 16] = (__bf16)h;
        }
      }
    }
  }
}

// stage 2, 64x64 tile — K9 schedule (B 2 loads/iter -> vmcnt(2)).
__global__ __launch_bounds__(256, 4) void gemm_stage2(
    const __bf16* __restrict__ he, const __bf16* __restrict__ hs, const int* __restrict__ counts,
    const int* __restrict__ offs, const __bf16* __restrict__ dw_t,
    const __bf16* __restrict__ sdw_t, __bf16* __restrict__ eo, __bf16* __restrict__ so) {
  __shared__ __align__(16) __bf16 Alds[64 * 64];      // 8KB
  __shared__ __align__(16) __bf16 Blds[2 * 64 * 64];  // 16KB (dbuf)
  int z = blockIdx.z, bx = blockIdx.x, m0 = blockIdx.y * 64;
  const __bf16 *A, *Bp;
  __bf16* Cp;
  int rowOff, M, K;
  if (z < E_NUM) {
    M = counts[z];
    if (m0 >= M) return;
    A = he;
    rowOff = offs[z];
    K = I_DIM;
    Bp = dw_t + (size_t)z * H_DIM * I_DIM;
    Cp = eo;
  } else {
    A = hs;
    rowOff = 0;
    M = T_TOK;
    K = SI_DIM;
    Bp = sdw_t;
    Cp = so;
  }
  int n0 = bx * 64;
  int tid = threadIdx.x;
  int wave = tid >> 6, lane = tid & 63;
  int rsub = lane >> 3, chunk = lane & 7;
  int sch = (chunk ^ rsub) * 8;
  size_t aB[2], bB[2];
#pragma unroll
  for (int j = 0; j < 2; j++) {
    int r = wave * 16 + j * 8 + rsub;
    int ar = m0 + r;
    ar = ar < M - 1 ? ar : M - 1;
    aB[j] = (size_t)(rowOff + ar) * K + sch;
    bB[j] = (size_t)(n0 + r) * K + sch;
  }
  int wm = (wave >> 1) * 32, wn = (wave & 1) * 32;
  int rl = lane & 15, gq = lane >> 4;
  int xa = rl & 7;

  auto STAGE_A = [&](int k0) {
#pragma unroll
    for (int j = 0; j < 2; j++) GL2L(A + aB[j] + k0, Alds + (wave * 16 + j * 8) * 64);
  };
  auto STAGE_B = [&](int k0, int b) {
#pragma unroll
    for (int j = 0; j < 2; j++)
      GL2L(Bp + bB[j] + k0, Blds + b * 4096 + (wave * 16 + j * 8) * 64);
  };

  f32x4 acc[2][2] = {};
  const int NT = K >> 6;
  STAGE_A(0);
  STAGE_B(0, 0);
  int buf = 0;
  for (int t = 0; t < NT; ++t) {
    if (t + 1 < NT) {
      STAGE_B((t + 1) << 6, buf ^ 1);
      asm volatile("s_waitcnt vmcnt(2)" ::: "memory");
    } else {
      asm volatile("s_waitcnt vmcnt(0)" ::: "memory");
    }
    BAR();
    const __bf16* Br = Blds + buf * 4096;
#pragma unroll
    for (int s = 0; s < 2; s++) {
      int lc = ((s * 4 + gq) ^ xa) * 8;
      bf16x8 af[2], bfr[2];
#pragma unroll
      for (int m = 0; m < 2; m++) af[m] = *(const bf16x8*)&Alds[(wm + m * 16 + rl) * 64 + lc];
#pragma unroll
      for (int n = 0; n < 2; n++) bfr[n] = *(const bf16x8*)&Br[(wn + n * 16 + rl) * 64 + lc];
#pragma unroll
      for (int m = 0; m < 2; m++)
#pragma unroll
        for (int n = 0; n < 2; n++)
          acc[m][n] =
              __builtin_amdgcn_mfma_f32_16x16x32_bf16(af[m], bfr[n], acc[m][n], 0, 0, 0);
    }
    BAR();
    if (t + 1 < NT) STAGE_A((t + 1) << 6);
    buf ^= 1;
  }
#pragma unroll
  for (int m = 0; m < 2; m++) {
#pragma unroll
    for (int b = 0; b < 4; b++) {
      int row = m0 + wm + m * 16 + gq * 4 + b;
      if (row < M) {
        size_t rb = (size_t)(rowOff + row) * H_DIM + n0 + wn + rl;
#pragma unroll
        for (int n = 0; n < 2; n++) Cp[rb + n * 16] = (__bf16)acc[m][n][b];
      }
    }
  }
}

// ---------------- combine: out = shared + sum_k w_k * eo[slot_k] ----------------
__global__ void combine_kernel(const __bf16* __restrict__ eo, const __bf16* __restrict__ so,
                               const int* __restrict__ slot_of_tk, const float* __restrict__ selW,
                               float* __restrict__ out) {
  int idx = blockIdx.x * blockDim.x + threadIdx.x;
  int t = idx >> 8;
  int h4 = (idx & 255) * 4;
  if (t >= T_TOK) return;
  bf16x4 sv = *(const bf16x4*)(so + (size_t)t * H_DIM + h4);
  float a0 = (float)sv[0], a1 = (float)sv[1], a2 = (float)sv[2], a3 = (float)sv[3];
#pragma unroll
  for (int k = 0; k < K_TOP; k++) {
    int slot = slot_of_tk[t * K_TOP + k];
    float w = selW[t * K_TOP + k];
    bf16x4 ev = *(const bf16x4*)(eo + (size_t)slot * H_DIM + h4);
    a0 += w * (float)ev[0];
    a1 += w * (float)ev[1];
    a2 += w * (float)ev[2];
    a3 += w * (float)ev[3];
  }
  *(float4*)(out + (size_t)t * H_DIM + h4) = make_float4(a0, a1, a2, a3);
}

extern "C" void kernel_launch(void* const* d_in, const int* in_sizes, int n_in, void* d_out,
                              int out_size, void* d_ws, size_t ws_size, hipStream_t stream) {
  const float* x = (const float*)d_in[0];
  const float* gate_weight = (const float*)d_in[1];
  const float* corr_bias = (const float*)d_in[2];
  const float* gate_w = (const float*)d_in[3];
  const float* up_w = (const float*)d_in[4];
  const float* down_w = (const float*)d_in[5];
  const float* sgw = (const float*)d_in[6];
  const float* suw = (const float*)d_in[7];
  const float* sdw = (const float*)d_in[8];
  float* out = (float*)d_out;
  float* logits_out = out + (size_t)T_TOK * H_DIM;

  char* wsb = (char*)d_ws;
  size_t o = 0;
  auto nxt = [&](size_t bytes) -> void* {
    void* p = wsb + o;
    o += (bytes + 1023) & ~(size_t)1023;
    return p;
  };
  const size_t EXP_ELE = (size_t)T_TOK * K_TOP * I_DIM;  // 4M
  const size_t SH_ELE = (size_t)T_TOK * SI_DIM;          // 2M
  __bf16* x_bf = (__bf16*)nxt((size_t)T_TOK * H_DIM * 2);
  __bf16* gw_t = (__bf16*)nxt((size_t)E_NUM * I_DIM * H_DIM * 2);  // [E, I, H]
  __bf16* uw_t = (__bf16*)nxt((size_t)E_NUM * I_DIM * H_DIM * 2);
  __bf16* dw_t = (__bf16*)nxt((size_t)E_NUM * H_DIM * I_DIM * 2);  // [E, H, I]
  __bf16* sgw_t = (__bf16*)nxt((size_t)SI_DIM * H_DIM * 2);        // [SI, H]
  __bf16* suw_t = (__bf16*)nxt((size_t)SI_DIM * H_DIM * 2);
  __bf16* sdw_t = (__bf16*)nxt((size_t)H_DIM * SI_DIM * 2);  // [H, SI]
  __bf16* h_all = (__bf16*)nxt((EXP_ELE + SH_ELE) * 2);
  __bf16* eo = (__bf16*)nxt((size_t)T_TOK * K_TOP * H_DIM * 2);
  __bf16* so = (__bf16*)nxt((size_t)T_TOK * H_DIM * 2);
  float* gwt_f = (float*)nxt((size_t)E_NUM * H_DIM * 4);
  int* counts = (int*)nxt(64);
  int* offs = (int*)nxt(128);
  int* selE = (int*)nxt((size_t)T_TOK * K_TOP * 4);
  float* selW = (float*)nxt((size_t)T_TOK * K_TOP * 4);
  int* slot_of_tk = (int*)nxt((size_t)T_TOK * K_TOP * 4);
  int* tok_of_slot = (int*)nxt((size_t)T_TOK * K_TOP * 4);
  __bf16* he = h_all;
  __bf16* hs = h_all + EXP_ELE;
  (void)ws_size;
  (void)in_sizes;
  (void)n_in;
  (void)out_size;

  transpose_all_kernel<<<6928, 256, 0, stream>>>(gate_w, up_w, down_w, sgw, suw, sdw,
                                                 gate_weight, gw_t, uw_t, dw_t, sgw_t, suw_t,
                                                 sdw_t, gwt_f);
  router_kernel<<<T_TOK / 8, 256, 0, stream>>>(x, gwt_f, corr_bias, logits_out, x_bf, selE,
                                               selW);
  count_place_kernel<<<1, 1024, 0, stream>>>(selE, counts, offs, slot_of_tk, tok_of_slot);

  gemm_stage1<<<dim3(8, 16, E_NUM + 2), 256, 0, stream>>>(x_bf, tok_of_slot, counts, offs, gw_t,
                                                          uw_t, sgw_t, suw_t, he, hs);
  gemm_stage2<<<dim3(16, 32, E_NUM + 1), 256, 0, stream>>>(he, hs, counts, offs, dw_t, sdw_t, eo,
                                                           so);

  combine_kernel<<<(T_TOK * H_DIM / 4) / 256, 256, 0, stream>>>(eo, so, slot_of_tk, selW, out);
}